// Round 7
// baseline (122.234 us; speedup 1.0000x reference)
//
#include <hip/hip_runtime.h>
#include <cstdint>

#define D_MODEL 768
#define NH      12
#define DKH     64
#define SEQ     2048
#define BS      2
#define MROWS   (BS*SEQ)   // 4096

typedef __bf16 bf16x8 __attribute__((ext_vector_type(8)));
typedef float  f32x4  __attribute__((ext_vector_type(4)));
typedef unsigned int u32_as1 __attribute__((address_space(1)));
typedef unsigned int u32_as3 __attribute__((address_space(3)));

__device__ __forceinline__ void gld16(const void* g, void* l) {
  __builtin_amdgcn_global_load_lds((const u32_as1*)g, (u32_as3*)l, 16, 0, 0);
}
__device__ __forceinline__ unsigned short f2bf(float x) {
  return __builtin_bit_cast(unsigned short, (__bf16)x);
}

// ---------------- fp32 -> bf16 converts (fused launches) --------------------
__global__ void cvt2(const float* __restrict__ a, const float* __restrict__ b,
                     unsigned short* __restrict__ oa, unsigned short* __restrict__ ob) {
  const float* in = blockIdx.y ? b : a;
  unsigned short* out = blockIdx.y ? ob : oa;
  int i = blockIdx.x * 256 + threadIdx.x;
  float4 v = reinterpret_cast<const float4*>(in)[i];
  ushort4 o; o.x = f2bf(v.x); o.y = f2bf(v.y); o.z = f2bf(v.z); o.w = f2bf(v.w);
  reinterpret_cast<ushort4*>(out)[i] = o;
}
__global__ void cvt4(const float* __restrict__ a, const float* __restrict__ b,
                     const float* __restrict__ c, const float* __restrict__ d,
                     unsigned short* __restrict__ oa, unsigned short* __restrict__ ob,
                     unsigned short* __restrict__ oc, unsigned short* __restrict__ od) {
  const float* in; unsigned short* out;
  switch (blockIdx.y) {
    case 0: in = a; out = oa; break;
    case 1: in = b; out = ob; break;
    case 2: in = c; out = oc; break;
    default: in = d; out = od; break;
  }
  int i = blockIdx.x * 256 + threadIdx.x;
  float4 v = reinterpret_cast<const float4*>(in)[i];
  ushort4 o; o.x = f2bf(v.x); o.y = f2bf(v.y); o.z = f2bf(v.z); o.w = f2bf(v.w);
  reinterpret_cast<ushort4*>(out)[i] = o;
}

// ---------------- 128x128 NT GEMM body (K=768), dbuf, 1 barrier/K-step ------
template<bool OUT_F32>
__device__ __forceinline__ void gemm128_body(
    const unsigned short* __restrict__ A, const unsigned short* __restrict__ B,
    const float* __restrict__ bias, int biasRow, void* __restrict__ Cout,
    int ldc, int m0, int n0)
{
  __shared__ alignas(16) char sA[2][16384];   // 128 rows x 128B
  __shared__ alignas(16) char sB[2][16384];
  const int tid = threadIdx.x;
  const int w = tid >> 6, l = tid & 63;
  const int g16 = l >> 4, c16 = l & 15;
  const int wr = (w >> 1) * 64, wc = (w & 1) * 64;

  auto stage = [&](const unsigned short* __restrict__ P, int p0, int kt, char* dst) {
#pragma unroll
    for (int i = 0; i < 4; i++) {
      int ch = w * 4 + i;                      // 16 chunks of 1KB
      int X = ch * 1024 + l * 16;
      int row = X >> 7;
      int sl = ((X >> 4) & 7) ^ (row & 7);     // inverse-swizzled source slot
      gld16(P + (size_t)(p0 + row) * 768 + kt + sl * 8, dst + ch * 1024);
    }
  };

  f32x4 acc[4][4];
#pragma unroll
  for (int m = 0; m < 4; m++)
#pragma unroll
    for (int n = 0; n < 4; n++) acc[m][n] = f32x4{0.f, 0.f, 0.f, 0.f};

  stage(A, m0, 0, sA[0]);
  stage(B, n0, 0, sB[0]);
  __syncthreads();
  int cur = 0;
  for (int kt = 0; kt < 768; kt += 64) {
    if (kt + 64 < 768) {
      stage(A, m0, kt + 64, sA[cur ^ 1]);
      stage(B, n0, kt + 64, sB[cur ^ 1]);
    }
    __builtin_amdgcn_s_setprio(1);
#pragma unroll
    for (int kk = 0; kk < 2; kk++) {
      bf16x8 af[4], bq[4];
#pragma unroll
      for (int m = 0; m < 4; m++) {
        int row = wr + m * 16 + c16, slot = kk * 4 + g16;
        af[m] = *(const bf16x8*)(sA[cur] + row * 128 + ((slot ^ (row & 7)) << 4));
      }
#pragma unroll
      for (int n = 0; n < 4; n++) {
        int row = wc + n * 16 + c16, slot = kk * 4 + g16;
        bq[n] = *(const bf16x8*)(sB[cur] + row * 128 + ((slot ^ (row & 7)) << 4));
      }
#pragma unroll
      for (int m = 0; m < 4; m++)
#pragma unroll
        for (int n = 0; n < 4; n++)
          acc[m][n] = __builtin_amdgcn_mfma_f32_16x16x32_bf16(af[m], bq[n], acc[m][n], 0, 0, 0);
    }
    __builtin_amdgcn_s_setprio(0);
    __syncthreads();
    cur ^= 1;
  }

#pragma unroll
  for (int m = 0; m < 4; m++)
#pragma unroll
    for (int n = 0; n < 4; n++)
#pragma unroll
      for (int r = 0; r < 4; r++) {
        int row = m0 + wr + m * 16 + g16 * 4 + r;
        int col = n0 + wc + n * 16 + c16;
        float v = acc[m][n][r] + (biasRow ? bias[row] : bias[col]);
        if constexpr (OUT_F32) ((float*)Cout)[(size_t)row * ldc + col] = v;
        else ((unsigned short*)Cout)[(size_t)row * ldc + col] = f2bf(v);
      }
}

// Fused QKV projections: grid dim3(192, 3); x XCD-swizzled (192 = 24 x 8).
__global__ __launch_bounds__(256, 2) void gemm_qkv(
    const unsigned short* __restrict__ q_bf, const unsigned short* __restrict__ c_bf,
    const unsigned short* __restrict__ wq, const unsigned short* __restrict__ wk,
    const unsigned short* __restrict__ wv,
    const float* __restrict__ bq, const float* __restrict__ bk,
    const float* __restrict__ bv,
    unsigned short* __restrict__ Qb, unsigned short* __restrict__ Kb,
    unsigned short* __restrict__ Vtb)
{
  const int x = blockIdx.x;
  const int lin = (x & 7) * 24 + (x >> 3);   // bijective
  const int tf = lin % 6, ts = lin / 6;
  const unsigned short *A, *B; const float* bias; unsigned short* C;
  int m0, n0, ldc, biasRow;
  switch (blockIdx.y) {
    case 0:  A = q_bf; B = wq;   bias = bq; C = Qb;  m0 = ts*128; n0 = tf*128; ldc = 768;  biasRow = 0; break;
    case 1:  A = c_bf; B = wk;   bias = bk; C = Kb;  m0 = ts*128; n0 = tf*128; ldc = 768;  biasRow = 0; break;
    default: A = wv;   B = c_bf; bias = bv; C = Vtb; m0 = tf*128; n0 = ts*128; ldc = 4096; biasRow = 1; break;
  }
  gemm128_body<false>(A, B, bias, biasRow, C, ldc, m0, n0);
}

__global__ __launch_bounds__(256, 2) void gemm_fc(
    const unsigned short* __restrict__ Ob, const unsigned short* __restrict__ wf,
    const float* __restrict__ fb, float* __restrict__ out)
{
  const int x = blockIdx.x;
  const int lin = (x & 7) * 24 + (x >> 3);
  const int tf = lin % 6, ts = lin / 6;
  gemm128_body<true>(Ob, wf, fb, 0, out, 768, ts * 128, tf * 128);
}

// ---------------- flash attention, in-block c-split --------------------------
// Grid 768 (XCD-swizzled as before), 512 threads = 2 groups x 4 waves.
// Group g handles c in [g*1024, g*1024+1024): partials are additive because
// softmax numerator has no running-max state. Single-buffered K/V per group
// (2 barriers/tile); 48KB LDS -> 3 blocks/CU x 8 waves = 24 waves/CU ceiling.
// End: group 1 dumps accO/accL to (dead) sK/sV, group 0 adds + stores.
__global__ __launch_bounds__(512, 6) void attn_kernel(
    const unsigned short* __restrict__ Qb, const unsigned short* __restrict__ Kb,
    const unsigned short* __restrict__ Vt, const int* __restrict__ cmask,
    unsigned short* __restrict__ Ob)
{
  __shared__ alignas(16) char sK[2][8192];   // [grp]: 64 x 64 bf16, swizzled rows
  __shared__ alignas(16) char sV[2][8192];   // [grp]: 64(dv) x 64(c)
  __shared__ alignas(16) char sP[2][8192];   // [grp]: per-wave 16 x 64
  const int tid = threadIdx.x, w = tid >> 6, l = tid & 63;
  const int wl = w & 3, grp = w >> 2;
  const int g16 = l >> 4, c16 = l & 15;
  const int flat = blockIdx.x;                 // 768
  const int xcd = flat & 7, sidx = flat >> 3;  // sidx 0..95
  const int p = xcd + 8 * (sidx >> 5);         // panel 0..23
  const int qt = sidx & 31;
  const int h = p % 12, b = p / 12;
  const int qrow0 = b * SEQ + qt * 64;
  const int cbase = b * SEQ + grp * 1024;      // this group's c-range start

  // Q fragments in registers (loop-invariant): q-row = wl*16 + c16
  bf16x8 qa[2];
  {
    const unsigned short* qp =
        Qb + (size_t)(qrow0 + wl * 16 + c16) * D_MODEL + h * DKH + g16 * 8;
    qa[0] = *(const bf16x8*)(qp);
    qa[1] = *(const bf16x8*)(qp + 32);
  }

  auto stageK = [&](int cg) {   // cg = global c row of tile start
#pragma unroll
    for (int i = 0; i < 2; i++) {
      int ch = wl * 2 + i;
      int X = ch * 1024 + l * 16;
      int row = X >> 7;
      int sl = ((X >> 4) & 7) ^ (row & 7);
      gld16(Kb + (size_t)(cg + row) * D_MODEL + h * DKH + sl * 8,
            sK[grp] + ch * 1024);
    }
  };
  auto stageV = [&](int cg) {
#pragma unroll
    for (int i = 0; i < 2; i++) {
      int ch = wl * 2 + i;
      int X = ch * 1024 + l * 16;
      int row = X >> 7;
      int sl = ((X >> 4) & 7) ^ (row & 7);
      gld16(Vt + (size_t)(h * DKH + row) * (size_t)MROWS + cg + sl * 8,
            sV[grp] + ch * 1024);
    }
  };

  f32x4 accO[4], accL;
#pragma unroll
  for (int n = 0; n < 4; n++) accO[n] = f32x4{0.f, 0.f, 0.f, 0.f};
  accL = f32x4{0.f, 0.f, 0.f, 0.f};
  const __bf16 one = (__bf16)1.0f;
  const bf16x8 vones = {one, one, one, one, one, one, one, one};

  for (int ct = 0; ct < 1024; ct += 64) {
    stageK(cbase + ct); stageV(cbase + ct);
    __syncthreads();          // vmcnt drain + barrier: tile visible

    int mk[4];
#pragma unroll
    for (int n = 0; n < 4; n++) mk[n] = cmask[cbase + ct + n * 16 + c16];

    // S = Q K^T (16 q-rows x 64 c-cols per wave)
    f32x4 s[4];
#pragma unroll
    for (int n = 0; n < 4; n++) s[n] = f32x4{0.f, 0.f, 0.f, 0.f};
    __builtin_amdgcn_s_setprio(1);
#pragma unroll
    for (int kk = 0; kk < 2; kk++) {
      bf16x8 kf[4];
#pragma unroll
      for (int n = 0; n < 4; n++) {
        int row = n * 16 + c16, slot = kk * 4 + g16;
        kf[n] = *(const bf16x8*)(sK[grp] + row * 128 + ((slot ^ (row & 7)) << 4));
      }
#pragma unroll
      for (int n = 0; n < 4; n++)
        s[n] = __builtin_amdgcn_mfma_f32_16x16x32_bf16(qa[kk], kf[n], s[n], 0, 0, 0);
    }
    __builtin_amdgcn_s_setprio(0);

    // no-max softmax numerator: p = exp(s/8), masked -> 0; straight to LDS
#pragma unroll
    for (int r = 0; r < 4; r++) {
      int prow = g16 * 4 + r;
#pragma unroll
      for (int n = 0; n < 4; n++) {
        float pv = mk[n] ? __expf(s[n][r] * 0.125f) : 0.f;
        int slot = n * 2 + (c16 >> 3);
        int addr = wl * 2048 + prow * 128 + ((slot ^ (prow & 7)) << 4) + (c16 & 7) * 2;
        *(__bf16*)(sP[grp] + addr) = (__bf16)pv;
      }
    }

    // O += P * V ; L += P * 1 (row-sum on the matrix pipe)
    __builtin_amdgcn_s_setprio(1);
#pragma unroll
    for (int kk = 0; kk < 2; kk++) {
      bf16x8 pa, vf[4];
      {
        int prow = c16, slot = kk * 4 + g16;
        pa = *(const bf16x8*)(sP[grp] + wl * 2048 + prow * 128 + ((slot ^ (prow & 7)) << 4));
      }
#pragma unroll
      for (int n = 0; n < 4; n++) {
        int vrow = n * 16 + c16, slot = kk * 4 + g16;
        vf[n] = *(const bf16x8*)(sV[grp] + vrow * 128 + ((slot ^ (vrow & 7)) << 4));
      }
#pragma unroll
      for (int n = 0; n < 4; n++)
        accO[n] = __builtin_amdgcn_mfma_f32_16x16x32_bf16(pa, vf[n], accO[n], 0, 0, 0);
      accL = __builtin_amdgcn_mfma_f32_16x16x32_bf16(pa, vones, accL, 0, 0, 0);
    }
    __builtin_amdgcn_s_setprio(0);

    __syncthreads();          // all reads done before next-tile restage
  }

  // cross-group combine through dead sK (accO, 16KB) / sV (accL, 4KB)
  {
    float* oArea = (float*)&sK[0][0];
    float* lArea = (float*)&sV[0][0];
    const int slot = wl * 64 + l;            // 0..255 within group
    if (grp == 1) {
#pragma unroll
      for (int n = 0; n < 4; n++)
        *reinterpret_cast<f32x4*>(&oArea[slot * 16 + n * 4]) = accO[n];
      *reinterpret_cast<f32x4*>(&lArea[slot * 4]) = accL;
    }
    __syncthreads();
    if (grp == 0) {
#pragma unroll
      for (int n = 0; n < 4; n++) {
        f32x4 o1 = *reinterpret_cast<const f32x4*>(&oArea[slot * 16 + n * 4]);
#pragma unroll
        for (int r = 0; r < 4; r++) accO[n][r] += o1[r];
      }
      f32x4 l1 = *reinterpret_cast<const f32x4*>(&lArea[slot * 4]);
#pragma unroll
      for (int r = 0; r < 4; r++) {
        float inv = 1.0f / (accL[r] + l1[r]);
#pragma unroll
        for (int n = 0; n < 4; n++) {
          int row = qrow0 + wl * 16 + g16 * 4 + r;
          int col = h * DKH + n * 16 + c16;
          Ob[(size_t)row * D_MODEL + col] = f2bf(accO[n][r] * inv);
        }
      }
    }
  }
}

// ---------------- launcher --------------------------------------------------
extern "C" void kernel_launch(void* const* d_in, const int* in_sizes, int n_in,
                              void* d_out, int out_size, void* d_ws, size_t ws_size,
                              hipStream_t stream) {
  const float* query   = (const float*)d_in[0];
  const float* context = (const float*)d_in[1];
  const int*   cmask   = (const int*)d_in[2];
  const float* Wq_w = (const float*)d_in[3];
  const float* Wq_b = (const float*)d_in[4];
  const float* Wk_w = (const float*)d_in[5];
  const float* Wk_b = (const float*)d_in[6];
  const float* Wv_w = (const float*)d_in[7];
  const float* Wv_b = (const float*)d_in[8];
  const float* fc_w = (const float*)d_in[9];
  const float* fc_b = (const float*)d_in[10];
  float* out = (float*)d_out;

  unsigned short* ws   = (unsigned short*)d_ws;
  const size_t NQ = (size_t)MROWS * D_MODEL;
  const size_t NW = (size_t)D_MODEL * D_MODEL;
  unsigned short* q_bf = ws;
  unsigned short* c_bf = q_bf + NQ;
  unsigned short* Qb   = c_bf + NQ;
  unsigned short* Kb   = Qb + NQ;
  unsigned short* Vtb  = Kb + NQ;
  unsigned short* Ob   = Vtb + NQ;
  unsigned short* wq   = Ob + NQ;
  unsigned short* wk   = wq + NW;
  unsigned short* wv   = wk + NW;
  unsigned short* wf   = wv + NW;

  cvt2<<<dim3(NQ / 4 / 256, 2), 256, 0, stream>>>(query, context, q_bf, c_bf);
  cvt4<<<dim3(NW / 4 / 256, 4), 256, 0, stream>>>(Wq_w, Wk_w, Wv_w, fc_w, wq, wk, wv, wf);

  // Q/K/V projections fused: y=0 Q, y=1 K, y=2 V^T
  gemm_qkv<<<dim3(192, 3), 256, 0, stream>>>(
      q_bf, c_bf, wq, wk, wv, Wq_b, Wk_b, Wv_b, Qb, Kb, Vtb);

  attn_kernel<<<768, 512, 0, stream>>>(Qb, Kb, Vtb, cmask, Ob);

  // out = O @ fc^T + fb (f32)
  gemm_fc<<<192, 256, 0, stream>>>(Ob, wf, fc_b, out);
}

// Round 8
// 97.467 us; speedup vs baseline: 1.2541x; 1.2541x over previous
//
#include <hip/hip_runtime.h>
#include <cstdint>

#define D_MODEL 768
#define NH      12
#define DKH     64
#define SEQ     2048
#define BS      2
#define MROWS   (BS*SEQ)   // 4096

typedef __bf16 bf16x8 __attribute__((ext_vector_type(8)));
typedef float  f32x4  __attribute__((ext_vector_type(4)));
typedef unsigned int u32_as1 __attribute__((address_space(1)));
typedef unsigned int u32_as3 __attribute__((address_space(3)));

__device__ __forceinline__ void gld16(const void* g, void* l) {
  __builtin_amdgcn_global_load_lds((const u32_as1*)g, (u32_as3*)l, 16, 0, 0);
}
__device__ __forceinline__ unsigned short f2bf(float x) {
  return __builtin_bit_cast(unsigned short, (__bf16)x);
}

// ---------------- fp32 -> bf16 converts (fused launches) --------------------
__global__ void cvt2(const float* __restrict__ a, const float* __restrict__ b,
                     unsigned short* __restrict__ oa, unsigned short* __restrict__ ob) {
  const float* in = blockIdx.y ? b : a;
  unsigned short* out = blockIdx.y ? ob : oa;
  int i = blockIdx.x * 256 + threadIdx.x;
  float4 v = reinterpret_cast<const float4*>(in)[i];
  ushort4 o; o.x = f2bf(v.x); o.y = f2bf(v.y); o.z = f2bf(v.z); o.w = f2bf(v.w);
  reinterpret_cast<ushort4*>(out)[i] = o;
}
__global__ void cvt4(const float* __restrict__ a, const float* __restrict__ b,
                     const float* __restrict__ c, const float* __restrict__ d,
                     unsigned short* __restrict__ oa, unsigned short* __restrict__ ob,
                     unsigned short* __restrict__ oc, unsigned short* __restrict__ od) {
  const float* in; unsigned short* out;
  switch (blockIdx.y) {
    case 0: in = a; out = oa; break;
    case 1: in = b; out = ob; break;
    case 2: in = c; out = oc; break;
    default: in = d; out = od; break;
  }
  int i = blockIdx.x * 256 + threadIdx.x;
  float4 v = reinterpret_cast<const float4*>(in)[i];
  ushort4 o; o.x = f2bf(v.x); o.y = f2bf(v.y); o.z = f2bf(v.z); o.w = f2bf(v.w);
  reinterpret_cast<ushort4*>(out)[i] = o;
}

// ---------------- 64x128 NT GEMM body (K=768), dbuf, 1 barrier/K-step -------
// C[m,n] = sum_k A[m,k]*B[n,k] + bias. 4 waves (2x2 of 32x64), BK=64,
// 48KB LDS -> 3 blocks/CU. Rows 128B, XOR-swizzled; global_load_lds staged.
template<bool OUT_F32>
__device__ __forceinline__ void gemm64x128_body(
    const unsigned short* __restrict__ A, const unsigned short* __restrict__ B,
    const float* __restrict__ bias, int biasRow, void* __restrict__ Cout,
    int ldc, int m0, int n0)
{
  __shared__ alignas(16) char sA[2][8192];    // 64 rows x 128B
  __shared__ alignas(16) char sB[2][16384];   // 128 rows x 128B
  const int tid = threadIdx.x;
  const int w = tid >> 6, l = tid & 63;
  const int g16 = l >> 4, c16 = l & 15;
  const int wr = (w >> 1) * 32, wc = (w & 1) * 64;

  auto stageA = [&](int kt, char* dst) {
#pragma unroll
    for (int i = 0; i < 2; i++) {
      int ch = w * 2 + i;                      // 8 chunks of 1KB
      int X = ch * 1024 + l * 16;
      int row = X >> 7;
      int sl = ((X >> 4) & 7) ^ (row & 7);
      gld16(A + (size_t)(m0 + row) * 768 + kt + sl * 8, dst + ch * 1024);
    }
  };
  auto stageB = [&](int kt, char* dst) {
#pragma unroll
    for (int i = 0; i < 4; i++) {
      int ch = w * 4 + i;                      // 16 chunks of 1KB
      int X = ch * 1024 + l * 16;
      int row = X >> 7;
      int sl = ((X >> 4) & 7) ^ (row & 7);
      gld16(B + (size_t)(n0 + row) * 768 + kt + sl * 8, dst + ch * 1024);
    }
  };

  f32x4 acc[2][4];
#pragma unroll
  for (int m = 0; m < 2; m++)
#pragma unroll
    for (int n = 0; n < 4; n++) acc[m][n] = f32x4{0.f, 0.f, 0.f, 0.f};

  stageA(0, sA[0]);
  stageB(0, sB[0]);
  __syncthreads();
  int cur = 0;
  for (int kt = 0; kt < 768; kt += 64) {
    if (kt + 64 < 768) {
      stageA(kt + 64, sA[cur ^ 1]);
      stageB(kt + 64, sB[cur ^ 1]);
    }
    __builtin_amdgcn_s_setprio(1);
#pragma unroll
    for (int kk = 0; kk < 2; kk++) {
      bf16x8 af[2], bq[4];
#pragma unroll
      for (int m = 0; m < 2; m++) {
        int row = wr + m * 16 + c16, slot = kk * 4 + g16;
        af[m] = *(const bf16x8*)(sA[cur] + row * 128 + ((slot ^ (row & 7)) << 4));
      }
#pragma unroll
      for (int n = 0; n < 4; n++) {
        int row = wc + n * 16 + c16, slot = kk * 4 + g16;
        bq[n] = *(const bf16x8*)(sB[cur] + row * 128 + ((slot ^ (row & 7)) << 4));
      }
#pragma unroll
      for (int m = 0; m < 2; m++)
#pragma unroll
        for (int n = 0; n < 4; n++)
          acc[m][n] = __builtin_amdgcn_mfma_f32_16x16x32_bf16(af[m], bq[n], acc[m][n], 0, 0, 0);
    }
    __builtin_amdgcn_s_setprio(0);
    __syncthreads();
    cur ^= 1;
  }

#pragma unroll
  for (int m = 0; m < 2; m++)
#pragma unroll
    for (int n = 0; n < 4; n++)
#pragma unroll
      for (int r = 0; r < 4; r++) {
        int row = m0 + wr + m * 16 + g16 * 4 + r;
        int col = n0 + wc + n * 16 + c16;
        float v = acc[m][n][r] + (biasRow ? bias[row] : bias[col]);
        if constexpr (OUT_F32) ((float*)Cout)[(size_t)row * ldc + col] = v;
        else ((unsigned short*)Cout)[(size_t)row * ldc + col] = f2bf(v);
      }
}

// Fused QKV projections: grid dim3(384, 3); x XCD-swizzled (384 = 48 x 8;
// 384*y = 0 mod 8 so x&7 is still the XCD).
// y<2 (Q,K): 6 n-tiles(128) x 64 m-tiles(64); XCD owns all n x 8 m-rows.
// y=2 (V^T): 12 m-tiles(64, dv) x 32 n-tiles(128, c); XCD owns all m x 4 n.
__global__ __launch_bounds__(256, 2) void gemm_qkv(
    const unsigned short* __restrict__ q_bf, const unsigned short* __restrict__ c_bf,
    const unsigned short* __restrict__ wq, const unsigned short* __restrict__ wk,
    const unsigned short* __restrict__ wv,
    const float* __restrict__ bq, const float* __restrict__ bk,
    const float* __restrict__ bv,
    unsigned short* __restrict__ Qb, unsigned short* __restrict__ Kb,
    unsigned short* __restrict__ Vtb)
{
  const int x = blockIdx.x;
  const int lin = (x & 7) * 48 + (x >> 3);   // bijective 0..383
  if (blockIdx.y == 0) {
    gemm64x128_body<false>(q_bf, wq, bq, 0, Qb, 768, (lin / 6) * 64, (lin % 6) * 128);
  } else if (blockIdx.y == 1) {
    gemm64x128_body<false>(c_bf, wk, bk, 0, Kb, 768, (lin / 6) * 64, (lin % 6) * 128);
  } else {
    gemm64x128_body<false>(wv, c_bf, bv, 1, Vtb, 4096, (lin % 12) * 64, (lin / 12) * 128);
  }
}

__global__ __launch_bounds__(256, 2) void gemm_fc(
    const unsigned short* __restrict__ Ob, const unsigned short* __restrict__ wf,
    const float* __restrict__ fb, float* __restrict__ out)
{
  const int x = blockIdx.x;
  const int lin = (x & 7) * 48 + (x >> 3);
  gemm64x128_body<true>(Ob, wf, fb, 0, out, 768, (lin / 6) * 64, (lin % 6) * 128);
}

// ---------------- flash attention (round-6, passing, byte-identical) --------
__global__ __launch_bounds__(256, 4) void attn_kernel(
    const unsigned short* __restrict__ Qb, const unsigned short* __restrict__ Kb,
    const unsigned short* __restrict__ Vt, const int* __restrict__ cmask,
    unsigned short* __restrict__ Ob)
{
  __shared__ alignas(16) char sK[2][8192];   // 64 x 64 bf16, swizzled rows
  __shared__ alignas(16) char sV[2][8192];   // 64(dv) x 64(c)
  __shared__ alignas(16) char sP[8192];      // per-wave 16 x 64
  const int tid = threadIdx.x, w = tid >> 6, l = tid & 63;
  const int g16 = l >> 4, c16 = l & 15;
  const int flat = blockIdx.x;                 // 768
  const int xcd = flat & 7, sidx = flat >> 3;  // sidx 0..95
  const int p = xcd + 8 * (sidx >> 5);         // panel 0..23
  const int qt = sidx & 31;
  const int h = p % 12, b = p / 12;
  const int qrow0 = b * SEQ + qt * 64;
  const int crow0 = b * SEQ;

  bf16x8 qa[2];
  {
    const unsigned short* qp =
        Qb + (size_t)(qrow0 + w * 16 + c16) * D_MODEL + h * DKH + g16 * 8;
    qa[0] = *(const bf16x8*)(qp);
    qa[1] = *(const bf16x8*)(qp + 32);
  }

  auto stageK = [&](int ct, int buf) {
#pragma unroll
    for (int i = 0; i < 2; i++) {
      int ch = w * 2 + i;
      int X = ch * 1024 + l * 16;
      int row = X >> 7;
      int sl = ((X >> 4) & 7) ^ (row & 7);
      gld16(Kb + (size_t)(crow0 + ct + row) * D_MODEL + h * DKH + sl * 8,
            sK[buf] + ch * 1024);
    }
  };
  auto stageV = [&](int ct, int buf) {
#pragma unroll
    for (int i = 0; i < 2; i++) {
      int ch = w * 2 + i;
      int X = ch * 1024 + l * 16;
      int row = X >> 7;
      int sl = ((X >> 4) & 7) ^ (row & 7);
      gld16(Vt + (size_t)(h * DKH + row) * (size_t)MROWS + crow0 + ct + sl * 8,
            sV[buf] + ch * 1024);
    }
  };

  f32x4 accO[4], accL;
#pragma unroll
  for (int n = 0; n < 4; n++) accO[n] = f32x4{0.f, 0.f, 0.f, 0.f};
  accL = f32x4{0.f, 0.f, 0.f, 0.f};
  const __bf16 one = (__bf16)1.0f;
  const bf16x8 vones = {one, one, one, one, one, one, one, one};

  stageK(0, 0); stageV(0, 0);
  __syncthreads();
  int cur = 0;

  for (int ct = 0; ct < SEQ; ct += 64) {
    if (ct + 64 < SEQ) { stageK(ct + 64, cur ^ 1); stageV(ct + 64, cur ^ 1); }

    int mk[4];
#pragma unroll
    for (int n = 0; n < 4; n++) mk[n] = cmask[crow0 + ct + n * 16 + c16];

    f32x4 s[4];
#pragma unroll
    for (int n = 0; n < 4; n++) s[n] = f32x4{0.f, 0.f, 0.f, 0.f};
    __builtin_amdgcn_s_setprio(1);
#pragma unroll
    for (int kk = 0; kk < 2; kk++) {
      bf16x8 kf[4];
#pragma unroll
      for (int n = 0; n < 4; n++) {
        int row = n * 16 + c16, slot = kk * 4 + g16;
        kf[n] = *(const bf16x8*)(sK[cur] + row * 128 + ((slot ^ (row & 7)) << 4));
      }
#pragma unroll
      for (int n = 0; n < 4; n++)
        s[n] = __builtin_amdgcn_mfma_f32_16x16x32_bf16(qa[kk], kf[n], s[n], 0, 0, 0);
    }
    __builtin_amdgcn_s_setprio(0);

    // no-max softmax numerator: p = exp(s/8), masked -> 0; straight to LDS
#pragma unroll
    for (int r = 0; r < 4; r++) {
      int prow = g16 * 4 + r;
#pragma unroll
      for (int n = 0; n < 4; n++) {
        float pv = mk[n] ? __expf(s[n][r] * 0.125f) : 0.f;
        int slot = n * 2 + (c16 >> 3);
        int addr = w * 2048 + prow * 128 + ((slot ^ (prow & 7)) << 4) + (c16 & 7) * 2;
        *(__bf16*)(sP + addr) = (__bf16)pv;
      }
    }

    // O += P * V ; L += P * 1 (row-sum on the matrix pipe)
    __builtin_amdgcn_s_setprio(1);
#pragma unroll
    for (int kk = 0; kk < 2; kk++) {
      bf16x8 pa, vf[4];
      {
        int prow = c16, slot = kk * 4 + g16;
        pa = *(const bf16x8*)(sP + w * 2048 + prow * 128 + ((slot ^ (prow & 7)) << 4));
      }
#pragma unroll
      for (int n = 0; n < 4; n++) {
        int vrow = n * 16 + c16, slot = kk * 4 + g16;
        vf[n] = *(const bf16x8*)(sV[cur] + vrow * 128 + ((slot ^ (vrow & 7)) << 4));
      }
#pragma unroll
      for (int n = 0; n < 4; n++)
        accO[n] = __builtin_amdgcn_mfma_f32_16x16x32_bf16(pa, vf[n], accO[n], 0, 0, 0);
      accL = __builtin_amdgcn_mfma_f32_16x16x32_bf16(pa, vones, accL, 0, 0, 0);
    }
    __builtin_amdgcn_s_setprio(0);

    __syncthreads();
    cur ^= 1;
  }

#pragma unroll
  for (int r = 0; r < 4; r++) {
    float inv = 1.0f / accL[r];
#pragma unroll
    for (int n = 0; n < 4; n++) {
      int row = qrow0 + w * 16 + g16 * 4 + r;
      int col = h * DKH + n * 16 + c16;
      Ob[(size_t)row * D_MODEL + col] = f2bf(accO[n][r] * inv);
    }
  }
}

// ---------------- launcher --------------------------------------------------
extern "C" void kernel_launch(void* const* d_in, const int* in_sizes, int n_in,
                              void* d_out, int out_size, void* d_ws, size_t ws_size,
                              hipStream_t stream) {
  const float* query   = (const float*)d_in[0];
  const float* context = (const float*)d_in[1];
  const int*   cmask   = (const int*)d_in[2];
  const float* Wq_w = (const float*)d_in[3];
  const float* Wq_b = (const float*)d_in[4];
  const float* Wk_w = (const float*)d_in[5];
  const float* Wk_b = (const float*)d_in[6];
  const float* Wv_w = (const float*)d_in[7];
  const float* Wv_b = (const float*)d_in[8];
  const float* fc_w = (const float*)d_in[9];
  const float* fc_b = (const float*)d_in[10];
  float* out = (float*)d_out;

  unsigned short* ws   = (unsigned short*)d_ws;
  const size_t NQ = (size_t)MROWS * D_MODEL;
  const size_t NW = (size_t)D_MODEL * D_MODEL;
  unsigned short* q_bf = ws;
  unsigned short* c_bf = q_bf + NQ;
  unsigned short* Qb   = c_bf + NQ;
  unsigned short* Kb   = Qb + NQ;
  unsigned short* Vtb  = Kb + NQ;
  unsigned short* Ob   = Vtb + NQ;
  unsigned short* wq   = Ob + NQ;
  unsigned short* wk   = wq + NW;
  unsigned short* wv   = wk + NW;
  unsigned short* wf   = wv + NW;

  cvt2<<<dim3(NQ / 4 / 256, 2), 256, 0, stream>>>(query, context, q_bf, c_bf);
  cvt4<<<dim3(NW / 4 / 256, 4), 256, 0, stream>>>(Wq_w, Wk_w, Wv_w, fc_w, wq, wk, wv, wf);

  // Q/K/V projections fused: y=0 Q, y=1 K, y=2 V^T
  gemm_qkv<<<dim3(384, 3), 256, 0, stream>>>(
      q_bf, c_bf, wq, wk, wv, Wq_b, Wk_b, Wv_b, Qb, Kb, Vtb);

  attn_kernel<<<768, 256, 0, stream>>>(Qb, Kb, Vtb, cmask, Ob);

  // out = O @ fc^T + fb (f32)
  gemm_fc<<<384, 256, 0, stream>>>(Ob, wf, fc_b, out);
}